// Round 14
// baseline (79.347 us; speedup 1.0000x reference)
//
#include <hip/hip_runtime.h>
#include <hip/hip_bf16.h>

typedef __bf16 bf16_t;
typedef __bf16 bf16x4 __attribute__((ext_vector_type(4)));
typedef __bf16 bf16x8 __attribute__((ext_vector_type(8)));
typedef float f32x4 __attribute__((ext_vector_type(4)));

#define S_LEN 2048
#define DMODEL 1024
#define NHEADS 16
#define HDIM 64
#define BROWS 4096   // B * S
#define QKVN 3072    // fused QKV output width

__device__ __forceinline__ void async16(const void* g, void* l) {
  __builtin_amdgcn_global_load_lds(
      (const __attribute__((address_space(1))) void*)g,
      (__attribute__((address_space(3))) void*)l, 16, 0, 0);
}

// ------------- weights-only f32 -> bf16 conversion (Wq,Wk,Wv,Wo) -----------
// x is no longer converted: QKV consumes f32 x directly (fused cvt).
__global__ __launch_bounds__(256) void cvt_w_kernel(
    const float* __restrict__ Wq, const float* __restrict__ Wk,
    const float* __restrict__ Wv, const float* __restrict__ Wo,
    bf16_t* __restrict__ dst) {
  const int i = blockIdx.x * 256 + threadIdx.x;  // float4 index < 1048576
  constexpr int WN4 = (DMODEL * DMODEL) / 4;     // 262144
  const int w = i >> 18;
  const size_t off = (size_t)(i & (WN4 - 1));
  const float* src = (w == 0) ? Wq : (w == 1) ? Wk : (w == 2) ? Wv : Wo;
  const float4 v = *(const float4*)(src + off * 4);
  bf16x4 o;
  o[0] = (bf16_t)v.x;
  o[1] = (bf16_t)v.y;
  o[2] = (bf16_t)v.z;
  o[3] = (bf16_t)v.w;
  *(bf16x4*)(dst + (size_t)i * 4) = o;
}

// ============ 256x192 GEMM (QKV): f32 A fused-convert staging ===============
// r13 loop kept (2 barriers/tile, VMC->BARR->reads discipline).  A staged
// reg-path: global f32 dwordx4 -> cvt -> swizzled ds_write_b128 (write-side
// swizzle slot^(row&7) == read swizzle).  B staged via global_load_lds from
// pre-converted bf16 ws (pre-swizzled source, linear dest) as before.
#define BARR __builtin_amdgcn_s_barrier()
#define LGKM0 asm volatile("s_waitcnt lgkmcnt(0)" ::: "memory")
#define VMC3 asm volatile("s_waitcnt vmcnt(3)" ::: "memory")
#define VMC0 asm volatile("s_waitcnt vmcnt(0)" ::: "memory")

__global__ __launch_bounds__(512, 2) void gemm_qkv256_kernel(
    const float* __restrict__ X, const bf16_t* __restrict__ W,
    const float* __restrict__ bq, const float* __restrict__ bk,
    const float* __restrict__ bv, bf16_t* __restrict__ C) {
  constexpr int Kd = 1024;
  __shared__ char lds[114688];  // A: 2*256*128B = 64KB, B: 2*192*128B = 48KB
  char* ldsA = lds;
  char* ldsB = lds + 65536;

  const int m0 = blockIdx.x * 256;
  const int n0 = blockIdx.y * 192;

  const int tid = threadIdx.x;
  const int lane = tid & 63;
  const int wid = tid >> 6;
  const int wr = wid >> 2;  // 0..1 (128 rows)
  const int wc = wid & 3;   // 0..3 (48 cols)
  const int fr = lane & 15;
  const int l16 = lane >> 4;

  f32x4 acc[8][3] = {};
  bf16x8 aS0[4][2], aS1[4][2], bB[3][2];
  float4 aLd[8];  // staged f32 A data (2 halves x 2 jobs x 2 float4)

  // issue A f32 loads for K-tile kt (8 dwordx4/thread, coalesced 256B rows)
  auto issueA = [&](int kt) {
#pragma unroll
    for (int h = 0; h < 2; ++h)
#pragma unroll
      for (int l = 0; l < 2; ++l) {
        const int s = l * 512 + tid;
        const int row = s >> 3, slot = s & 7;
        const float* p =
            X + (size_t)(m0 + h * 128 + row) * Kd + kt * 64 + slot * 8;
        aLd[(h * 2 + l) * 2] = *(const float4*)p;
        aLd[(h * 2 + l) * 2 + 1] = *(const float4*)(p + 4);
      }
  };
  // convert + write A into buf at swizzled slots (4 b128 writes/thread)
  auto writeA = [&](int buf) {
#pragma unroll
    for (int h = 0; h < 2; ++h)
#pragma unroll
      for (int l = 0; l < 2; ++l) {
        const int s = l * 512 + tid;
        const int row = s >> 3, slot = s & 7;
        const float4 f0 = aLd[(h * 2 + l) * 2];
        const float4 f1 = aLd[(h * 2 + l) * 2 + 1];
        bf16x8 v;
        v[0] = (bf16_t)f0.x; v[1] = (bf16_t)f0.y;
        v[2] = (bf16_t)f0.z; v[3] = (bf16_t)f0.w;
        v[4] = (bf16_t)f1.x; v[5] = (bf16_t)f1.y;
        v[6] = (bf16_t)f1.z; v[7] = (bf16_t)f1.w;
        *(bf16x8*)(ldsA + buf * 32768 + h * 16384 + row * 128 +
                   ((slot ^ (row & 7)) << 4)) = v;
      }
  };
  auto stageB = [&](int buf, int th, int kt) {
    const int r = tid >> 3;  // 0..63
    const int slot = tid & 7;
    async16((const char*)(W + (size_t)(n0 + th * 64 + r) * Kd + kt * 64 +
                          ((slot ^ (r & 7)) << 3)),
            ldsB + buf * 24576 + th * 8192 + r * 128 + slot * 16);
  };

  auto rdA = [&](int buf, int row, int ks) -> bf16x8 {
    return *(const bf16x8*)(ldsA + buf * 32768 + row * 128 +
                            ((((ks << 2) + l16) ^ (row & 7)) << 4));
  };
  auto rdB = [&](int buf, int row, int ks) -> bf16x8 {
    return *(const bf16x8*)(ldsB + buf * 24576 + row * 128 +
                            ((((ks << 2) + l16) ^ (row & 7)) << 4));
  };

  // ---- prologue: A(0) reg-stage, B(0)/B(1) gload_lds, A(1) issue; drain.
  issueA(0);
  stageB(0, 0, 0);
  stageB(0, 1, 0);
  stageB(0, 2, 0);
  stageB(1, 0, 1);
  stageB(1, 1, 1);
  stageB(1, 2, 1);
  writeA(0);  // compiler inserts vmcnt for aLd deps
  issueA(1);
  VMC0;   // one-time full drain: B0,B1 in LDS; A1 in regs (ordering-proof)
  LGKM0;  // A0 ds_writes committed
  BARR;   // tile0 certified across all waves
  writeA(1);  // A(1) -> buf1; certified by iter0's LGKM0+BARR#1

#pragma unroll 1
  for (int t = 0; t < 16; ++t) {
    const int buf = t & 1;
    // --- reads: full tile t (22 x ds_read_b128)
#pragma unroll
    for (int m_ = 0; m_ < 4; ++m_)
#pragma unroll
      for (int ks_ = 0; ks_ < 2; ++ks_) {
        aS0[m_][ks_] = rdA(buf, wr * 128 + m_ * 16 + fr, ks_);
        aS1[m_][ks_] = rdA(buf, wr * 128 + 64 + m_ * 16 + fr, ks_);
      }
#pragma unroll
    for (int n_ = 0; n_ < 3; ++n_)
#pragma unroll
      for (int ks_ = 0; ks_ < 2; ++ks_)
        bB[n_][ks_] = rdB(buf, wc * 48 + n_ * 16 + fr, ks_);
    // --- issue A(t+2) f32 loads (latency hides under MFMA)
    if (t + 2 < 16) issueA(t + 2);
    LGKM0;  // own reads retired...
    BARR;   // ...all waves' reads retired -> buf safe to overwrite
    // --- stage B(t+2) via gload_lds into freed region
    if (t + 2 < 16) {
      stageB(buf, 0, t + 2);
      stageB(buf, 1, t + 2);
      stageB(buf, 2, t + 2);
    }
    // --- 48 MFMA
    __builtin_amdgcn_s_setprio(1);
#pragma unroll
    for (int m_ = 0; m_ < 4; ++m_)
#pragma unroll
      for (int n_ = 0; n_ < 3; ++n_) {
#pragma unroll
        for (int ks_ = 0; ks_ < 2; ++ks_)
          acc[m_][n_] = __builtin_amdgcn_mfma_f32_16x16x32_bf16(
              aS0[m_][ks_], bB[n_][ks_], acc[m_][n_], 0, 0, 0);
#pragma unroll
        for (int ks_ = 0; ks_ < 2; ++ks_)
          acc[4 + m_][n_] = __builtin_amdgcn_mfma_f32_16x16x32_bf16(
              aS1[m_][ks_], bB[n_][ks_], acc[4 + m_][n_], 0, 0, 0);
      }
    __builtin_amdgcn_s_setprio(0);
    // --- certify tile t+1; convert+write A(t+2)
    if (t < 15) {
      if (t + 2 < 16) {
        VMC3;  // retires B(t+1) (oldest 3) in any issue order; A auto-dep'd
      } else {
        VMC0;  // t=14: only B(15) outstanding
      }
      if (t + 2 < 16) writeA(buf);  // A(t+2) -> buf (vacated region)
      LGKM0;                        // A-writes committed (and reads long done)
      BARR;                         // certifies tile t+1 (B vmcnt'd + A written)
    }
  }

  // epilogue: C/D layout col = lane&15, row = (lane>>4)*4 + reg  [m89]
  const int cr = l16 * 4;
#pragma unroll
  for (int nf = 0; nf < 3; ++nf) {
    const int col = n0 + wc * 48 + nf * 16 + fr;  // 0..3071
    const int mat = col >> 10;
    const float* bp = (mat == 0) ? bq : (mat == 1) ? bk : bv;
    const float bval = bp[col & 1023];
#pragma unroll
    for (int mf = 0; mf < 8; ++mf) {
      const int row = m0 + wr * 128 + mf * 16 + cr;
#pragma unroll
      for (int r = 0; r < 4; ++r)
        C[(size_t)(row + r) * QKVN + col] = (bf16_t)(acc[mf][nf][r] + bval);
    }
  }
}

// ============== 128x128 GEMM, 8 waves (O-projection, 2 waves/SIMD) ==========
__global__ __launch_bounds__(512) void gemm_o_kernel(
    const bf16_t* __restrict__ Adat, const bf16_t* __restrict__ W,
    const float* __restrict__ bias, float* __restrict__ out) {
  constexpr int Kd = 1024, Nd = 1024, BK = 32, NT = Kd / BK;
  __shared__ bf16_t ldsA[2][128 * BK];
  __shared__ bf16_t ldsB[2][128 * BK];

  const int m0 = blockIdx.x * 128;
  const int n0 = blockIdx.y * 128;

  const int tid = threadIdx.x;
  const int lane = tid & 63;
  const int wid = tid >> 6;
  const int wr = wid >> 2;  // 0..1 (64 rows each)
  const int wc = wid & 3;   // 0..3 (32 cols each)
  const int fr = lane & 15;
  const int ko = (lane >> 4) * 8;

  f32x4 acc[4][2] = {};

  auto stage = [&](int buf, int t) {
    const int k0 = t * BK;
    const int row = tid >> 2;       // 0..127
    const int kb = (tid & 3) * 16;  // byte offset in 64B row
    async16((const char*)(Adat + (size_t)(m0 + row) * Kd + k0) + kb,
            (char*)ldsA[buf] + row * 64 + kb);
    async16((const char*)(W + (size_t)(n0 + row) * Kd + k0) + kb,
            (char*)ldsB[buf] + row * 64 + kb);
  };

  auto compute = [&](int buf) {
    bf16x8 af[4], bf[2];
#pragma unroll
    for (int i = 0; i < 4; ++i)
      af[i] = *(const bf16x8*)(ldsA[buf] + (wr * 64 + i * 16 + fr) * BK + ko);
#pragma unroll
    for (int j = 0; j < 2; ++j)
      bf[j] = *(const bf16x8*)(ldsB[buf] + (wc * 32 + j * 16 + fr) * BK + ko);
#pragma unroll
    for (int i = 0; i < 4; ++i)
#pragma unroll
      for (int j = 0; j < 2; ++j)
        acc[i][j] = __builtin_amdgcn_mfma_f32_16x16x32_bf16(af[i], bf[j],
                                                            acc[i][j], 0, 0, 0);
  };

  stage(0, 0);
  __syncthreads();
#pragma unroll 1
  for (int t = 0; t < NT; ++t) {
    if (t + 1 < NT) stage((t + 1) & 1, t + 1);
    compute(t & 1);
    __syncthreads();
  }

  const int cr = (lane >> 4) * 4;
#pragma unroll
  for (int j = 0; j < 2; ++j) {
    const int col = n0 + wc * 32 + j * 16 + fr;
    const float bval = bias[col];
#pragma unroll
    for (int i = 0; i < 4; ++i) {
#pragma unroll
      for (int r = 0; r < 4; ++r) {
        const int row = m0 + wr * 64 + i * 16 + cr + r;
        out[(size_t)row * Nd + col] = acc[i][j][r] + bval;
      }
    }
  }
}

// ---------------- local attention (thread-per-query, fused QKV in) ---------
#define CHUNK 256
#define TROWS 260

__global__ __launch_bounds__(256) void attn_kernel(
    const bf16_t* __restrict__ QKV, bf16_t* __restrict__ ctx) {
  __shared__ bf16_t ldsK[TROWS * HDIM];
  __shared__ bf16_t ldsV[TROWS * HDIM];

  const int tid = threadIdx.x;
  const int blk = blockIdx.x;
  const int chunk = blk & 7;
  const int bh = blk >> 3;
  const int h = bh & (NHEADS - 1);
  const int b = bh >> 4;
  const int s0 = chunk * CHUNK;

  const bf16_t* Kb = QKV + (size_t)b * S_LEN * QKVN + DMODEL + h * HDIM;
  const bf16_t* Vb = QKV + (size_t)b * S_LEN * QKVN + 2 * DMODEL + h * HDIM;

#pragma unroll
  for (int j = 0; j < 9; ++j) {
    const int i = j * 256 + tid;
    if (i < TROWS * 8) {
      const int tr = i >> 3;
      const int slot = i & 7;
      const int c = slot ^ (tr & 7);
      int gs = s0 - 2 + tr;
      gs = (gs < 0) ? 0 : (gs >= S_LEN ? S_LEN - 1 : gs);
      async16((const char*)(Kb + (size_t)gs * QKVN) + c * 16,
              (char*)ldsK + i * 16);
      async16((const char*)(Vb + (size_t)gs * QKVN) + c * 16,
              (char*)ldsV + i * 16);
    }
  }

  const int s = s0 + tid;
  const bf16_t* Qrow = QKV + ((size_t)(b * S_LEN) + s) * QKVN + h * HDIM;
  bf16x8 q8[8];
#pragma unroll
  for (int c = 0; c < 8; ++c) q8[c] = *(const bf16x8*)(Qrow + c * 8);
  float qf[64];
#pragma unroll
  for (int c = 0; c < 8; ++c)
#pragma unroll
    for (int e = 0; e < 8; ++e) qf[c * 8 + e] = (float)q8[c][e];

  __syncthreads();

  float sc[5];
#pragma unroll
  for (int jj = 0; jj < 5; ++jj) {
    const int tr = tid + jj;
    float d = 0.f;
#pragma unroll
    for (int c = 0; c < 8; ++c) {
      const bf16x8 k8 = *(const bf16x8*)(ldsK + tr * HDIM + (c ^ (tr & 7)) * 8);
#pragma unroll
      for (int e = 0; e < 8; ++e) d += qf[c * 8 + e] * (float)k8[e];
    }
    const int j = s - 2 + jj;
    sc[jj] = (j < 0 || j >= S_LEN) ? -1e30f : d * 0.125f;
  }

  float m = sc[0];
#pragma unroll
  for (int jj = 1; jj < 5; ++jj) m = fmaxf(m, sc[jj]);
  float p[5], l = 0.f;
#pragma unroll
  for (int jj = 0; jj < 5; ++jj) {
    p[jj] = __expf(sc[jj] - m);
    l += p[jj];
  }
  const float inv = 1.0f / l;
#pragma unroll
  for (int jj = 0; jj < 5; ++jj) p[jj] *= inv;

  float o[64];
#pragma unroll
  for (int e = 0; e < 64; ++e) o[e] = 0.f;
#pragma unroll
  for (int jj = 0; jj < 5; ++jj) {
    const int tr = tid + jj;
    const float pj = p[jj];
#pragma unroll
    for (int c = 0; c < 8; ++c) {
      const bf16x8 v8 = *(const bf16x8*)(ldsV + tr * HDIM + (c ^ (tr & 7)) * 8);
#pragma unroll
      for (int e = 0; e < 8; ++e) o[c * 8 + e] += pj * (float)v8[e];
    }
  }

  bf16_t* Crow = (bf16_t*)ctx + ((size_t)(b * S_LEN) + s) * DMODEL + h * HDIM;
#pragma unroll
  for (int c = 0; c < 8; ++c) {
    bf16x8 ov;
#pragma unroll
    for (int e = 0; e < 8; ++e) ov[e] = (bf16_t)o[c * 8 + e];
    *(bf16x8*)(Crow + c * 8) = ov;
  }
}

extern "C" void kernel_launch(void* const* d_in, const int* in_sizes, int n_in,
                              void* d_out, int out_size, void* d_ws,
                              size_t ws_size, hipStream_t stream) {
  const float* x = (const float*)d_in[0];
  const float* Wq = (const float*)d_in[1];
  const float* bq = (const float*)d_in[2];
  const float* Wk = (const float*)d_in[3];
  const float* bk = (const float*)d_in[4];
  const float* Wv = (const float*)d_in[5];
  const float* bv = (const float*)d_in[6];
  const float* Wo = (const float*)d_in[7];
  const float* bo = (const float*)d_in[8];
  float* out = (float*)d_out;

  const size_t mat = (size_t)BROWS * DMODEL;
  const size_t wmat = (size_t)DMODEL * DMODEL;
  bf16_t* Wqkv = (bf16_t*)d_ws;  // [Wqkv(3 wmat) | Wob | QKV | ctx]
  bf16_t* Wob = Wqkv + 3 * wmat;
  bf16_t* QKV = Wob + wmat;      // fused [4096][3072]
  bf16_t* ctx = QKV + 3 * mat;

  // weights-only conversion: 4*262144 float4 jobs -> 4096 blocks
  cvt_w_kernel<<<4096, 256, 0, stream>>>(Wq, Wk, Wv, Wo, Wqkv);
  // QKV: f32 x consumed directly (fused conversion in staging)
  gemm_qkv256_kernel<<<dim3(16, 16), 512, 0, stream>>>(x, Wqkv, bq, bk, bv,
                                                       QKV);
  attn_kernel<<<256, 256, 0, stream>>>(QKV, ctx);
  gemm_o_kernel<<<dim3(32, 8), 512, 0, stream>>>(ctx, Wob, bo, out);
}

// Round 15
// 73.392 us; speedup vs baseline: 1.0811x; 1.0811x over previous
//
#include <hip/hip_runtime.h>
#include <hip/hip_bf16.h>

typedef __bf16 bf16_t;
typedef __bf16 bf16x4 __attribute__((ext_vector_type(4)));
typedef __bf16 bf16x8 __attribute__((ext_vector_type(8)));
typedef float f32x4 __attribute__((ext_vector_type(4)));

#define S_LEN 2048
#define DMODEL 1024
#define NHEADS 16
#define HDIM 64
#define BROWS 4096   // B * S
#define QKVN 3072    // fused QKV output width

__device__ __forceinline__ void async16(const void* g, void* l) {
  __builtin_amdgcn_global_load_lds(
      (const __attribute__((address_space(1))) void*)g,
      (__attribute__((address_space(3))) void*)l, 16, 0, 0);
}

// ------------- fused f32 -> bf16 conversion (x, Wq, Wk, Wv, Wo) -------------
__global__ __launch_bounds__(256) void cvt_all_kernel(
    const float* __restrict__ x, const float* __restrict__ Wq,
    const float* __restrict__ Wk, const float* __restrict__ Wv,
    const float* __restrict__ Wo, bf16_t* __restrict__ dst) {
  const int i = blockIdx.x * 256 + threadIdx.x;  // float4 index
  constexpr int XN4 = (BROWS * DMODEL) / 4;      // 1048576
  constexpr int WN4 = (DMODEL * DMODEL) / 4;     // 262144
  const float* src;
  size_t off;
  if (i < XN4) {
    src = x;
    off = (size_t)i;
  } else {
    const int wi = i - XN4;
    const int w = wi >> 18;
    off = (size_t)(wi & (WN4 - 1));
    src = (w == 0) ? Wq : (w == 1) ? Wk : (w == 2) ? Wv : Wo;
  }
  const float4 v = *(const float4*)(src + off * 4);
  bf16x4 o;
  o[0] = (bf16_t)v.x;
  o[1] = (bf16_t)v.y;
  o[2] = (bf16_t)v.z;
  o[3] = (bf16_t)v.w;
  *(bf16x4*)(dst + (size_t)i * 4) = o;
}

// ========== 128x192 GEMM (QKV): 2 blocks/CU, independent barrier domains ====
// Round-15: r14 counters showed MfmaUtil 20%, VALUBusy 13%, occupancy 19% --
// a serialization kernel: 1 block/CU, 8 lockstepped waves, phases serial.
// Fix: 80KB LDS tile (128x192, BK=64, 256 thr) -> EXACTLY 2 blocks/CU.
// Two independent barrier domains per CU overlap read-phase with MFMA-phase.
// Loop kept verbatim from r13 (race-free): reads -> LGKM0 -> BARR#1 ->
// stage(t+2) -> MFMA -> VMC(<=10) -> BARR#2.  10 stage-instr/tile.
#define BARR __builtin_amdgcn_s_barrier()
#define LGKM0 asm volatile("s_waitcnt lgkmcnt(0)" ::: "memory")
#define VMC10 asm volatile("s_waitcnt vmcnt(10)" ::: "memory")
#define VMC0 asm volatile("s_waitcnt vmcnt(0)" ::: "memory")

__global__ __launch_bounds__(256, 2) void gemm_qkv_kernel(
    const bf16_t* __restrict__ A, const bf16_t* __restrict__ W,
    const float* __restrict__ bq, const float* __restrict__ bk,
    const float* __restrict__ bv, bf16_t* __restrict__ C) {
  constexpr int Kd = 1024;
  __shared__ char lds[81920];  // A: 2buf*16KB, B: 2buf*24KB = 80KB
  char* ldsA = lds;            // + buf*16384
  char* ldsB = lds + 32768;    // + buf*24576

  const int m0 = blockIdx.x * 128;
  const int n0 = blockIdx.y * 192;

  const int tid = threadIdx.x;
  const int lane = tid & 63;
  const int wid = tid >> 6;   // 0..3
  const int wr = wid >> 1;    // 0..1 (64 rows each)
  const int wc = wid & 1;     // 0..1 (96 cols each)
  const int fr = lane & 15;
  const int l16 = lane >> 4;

  f32x4 acc[4][6] = {};
  bf16x8 aS[4][2], bB[6][2];

  // A tile: 128 rows x 128B = 1024 chunks -> 4 instr/thread
  auto stageA = [&](int buf, int kt) {
#pragma unroll
    for (int l = 0; l < 4; ++l) {
      const int idx = l * 256 + tid;
      const int r = idx >> 3;  // 0..127
      const int slot = idx & 7;
      async16((const char*)(A + (size_t)(m0 + r) * Kd + kt * 64 +
                            ((slot ^ (r & 7)) << 3)),
              ldsA + buf * 16384 + r * 128 + slot * 16);
    }
  };
  // B tile: 192 rows x 128B = 1536 chunks -> 6 instr/thread
  auto stageB = [&](int buf, int kt) {
#pragma unroll
    for (int l = 0; l < 6; ++l) {
      const int idx = l * 256 + tid;
      const int r = idx >> 3;  // 0..191
      const int slot = idx & 7;
      async16((const char*)(W + (size_t)(n0 + r) * Kd + kt * 64 +
                            ((slot ^ (r & 7)) << 3)),
              ldsB + buf * 24576 + r * 128 + slot * 16);
    }
  };

  auto rdA = [&](int buf, int row, int ks) -> bf16x8 {
    return *(const bf16x8*)(ldsA + buf * 16384 + row * 128 +
                            ((((ks << 2) + l16) ^ (row & 7)) << 4));
  };
  auto rdB = [&](int buf, int row, int ks) -> bf16x8 {
    return *(const bf16x8*)(ldsB + buf * 24576 + row * 128 +
                            ((((ks << 2) + l16) ^ (row & 7)) << 4));
  };

  // prologue: tile0 -> buf0 (10 instr), tile1 -> buf1 (10); certify tile0.
  stageA(0, 0);
  stageB(0, 0);
  stageA(1, 1);
  stageB(1, 1);
  VMC10;  // 20 outstanding -> retire oldest 10 = all of tile0 (own)
  BARR;   // barrier-release certifies tile0 across all waves

#pragma unroll 1
  for (int t = 0; t < 16; ++t) {
    const int buf = t & 1;
    // --- reads: full tile t (8 A + 12 B = 20 x ds_read_b128 per wave)
#pragma unroll
    for (int m_ = 0; m_ < 4; ++m_)
#pragma unroll
      for (int ks_ = 0; ks_ < 2; ++ks_)
        aS[m_][ks_] = rdA(buf, wr * 64 + m_ * 16 + fr, ks_);
#pragma unroll
    for (int n_ = 0; n_ < 6; ++n_)
#pragma unroll
      for (int ks_ = 0; ks_ < 2; ++ks_)
        bB[n_][ks_] = rdB(buf, wc * 96 + n_ * 16 + fr, ks_);
    LGKM0;  // own reads retired...
    BARR;   // ...all waves' reads retired -> buf safe to overwrite
    // --- stage tile t+2 into the freed region
    if (t + 2 < 16) {
      stageA(buf, t + 2);
      stageB(buf, t + 2);
    }
    // --- 48 MFMA
    __builtin_amdgcn_s_setprio(1);
#pragma unroll
    for (int m_ = 0; m_ < 4; ++m_)
#pragma unroll
      for (int n_ = 0; n_ < 6; ++n_)
#pragma unroll
        for (int ks_ = 0; ks_ < 2; ++ks_)
          acc[m_][n_] = __builtin_amdgcn_mfma_f32_16x16x32_bf16(
              aS[m_][ks_], bB[n_][ks_], acc[m_][n_], 0, 0, 0);
    __builtin_amdgcn_s_setprio(0);
    // --- certify tile t+1 for next iteration (VMC -> BARR -> reads)
    if (t < 15) {
      if (t + 2 < 16) {
        VMC10;  // outstanding t+1's 10 + t+2's 10 -> retire t+1's
      } else {
        VMC0;   // t=14: only t15's 10 outstanding
      }
      BARR;
    }
  }

  // epilogue: C/D layout col = lane&15, row = (lane>>4)*4 + reg  [m89]
  const int cr = l16 * 4;
#pragma unroll
  for (int nf = 0; nf < 6; ++nf) {
    const int col = n0 + wc * 96 + nf * 16 + fr;  // 0..3071
    const int mat = col >> 10;
    const float* bp = (mat == 0) ? bq : (mat == 1) ? bk : bv;
    const float bval = bp[col & 1023];
#pragma unroll
    for (int mf = 0; mf < 4; ++mf) {
      const int row = m0 + wr * 64 + mf * 16 + cr;
#pragma unroll
      for (int r = 0; r < 4; ++r)
        C[(size_t)(row + r) * QKVN + col] = (bf16_t)(acc[mf][nf][r] + bval);
    }
  }
}

// ============== 128x128 GEMM, 8 waves (O-projection, 2 waves/SIMD) ==========
__global__ __launch_bounds__(512) void gemm_o_kernel(
    const bf16_t* __restrict__ Adat, const bf16_t* __restrict__ W,
    const float* __restrict__ bias, float* __restrict__ out) {
  constexpr int Kd = 1024, Nd = 1024, BK = 32, NT = Kd / BK;
  __shared__ bf16_t ldsA[2][128 * BK];
  __shared__ bf16_t ldsB[2][128 * BK];

  const int m0 = blockIdx.x * 128;
  const int n0 = blockIdx.y * 128;

  const int tid = threadIdx.x;
  const int lane = tid & 63;
  const int wid = tid >> 6;
  const int wr = wid >> 2;  // 0..1 (64 rows each)
  const int wc = wid & 3;   // 0..3 (32 cols each)
  const int fr = lane & 15;
  const int ko = (lane >> 4) * 8;

  f32x4 acc[4][2] = {};

  auto stage = [&](int buf, int t) {
    const int k0 = t * BK;
    const int row = tid >> 2;       // 0..127
    const int kb = (tid & 3) * 16;  // byte offset in 64B row
    async16((const char*)(Adat + (size_t)(m0 + row) * Kd + k0) + kb,
            (char*)ldsA[buf] + row * 64 + kb);
    async16((const char*)(W + (size_t)(n0 + row) * Kd + k0) + kb,
            (char*)ldsB[buf] + row * 64 + kb);
  };

  auto compute = [&](int buf) {
    bf16x8 af[4], bf[2];
#pragma unroll
    for (int i = 0; i < 4; ++i)
      af[i] = *(const bf16x8*)(ldsA[buf] + (wr * 64 + i * 16 + fr) * BK + ko);
#pragma unroll
    for (int j = 0; j < 2; ++j)
      bf[j] = *(const bf16x8*)(ldsB[buf] + (wc * 32 + j * 16 + fr) * BK + ko);
#pragma unroll
    for (int i = 0; i < 4; ++i)
#pragma unroll
      for (int j = 0; j < 2; ++j)
        acc[i][j] = __builtin_amdgcn_mfma_f32_16x16x32_bf16(af[i], bf[j],
                                                            acc[i][j], 0, 0, 0);
  };

  stage(0, 0);
  __syncthreads();
#pragma unroll 1
  for (int t = 0; t < NT; ++t) {
    if (t + 1 < NT) stage((t + 1) & 1, t + 1);
    compute(t & 1);
    __syncthreads();
  }

  const int cr = (lane >> 4) * 4;
#pragma unroll
  for (int j = 0; j < 2; ++j) {
    const int col = n0 + wc * 32 + j * 16 + fr;
    const float bval = bias[col];
#pragma unroll
    for (int i = 0; i < 4; ++i) {
#pragma unroll
      for (int r = 0; r < 4; ++r) {
        const int row = m0 + wr * 64 + i * 16 + cr + r;
        out[(size_t)row * Nd + col] = acc[i][j][r] + bval;
      }
    }
  }
}

// ---------------- local attention (thread-per-query, fused QKV in) ---------
#define CHUNK 256
#define TROWS 260

__global__ __launch_bounds__(256) void attn_kernel(
    const bf16_t* __restrict__ QKV, bf16_t* __restrict__ ctx) {
  __shared__ bf16_t ldsK[TROWS * HDIM];
  __shared__ bf16_t ldsV[TROWS * HDIM];

  const int tid = threadIdx.x;
  const int blk = blockIdx.x;
  const int chunk = blk & 7;
  const int bh = blk >> 3;
  const int h = bh & (NHEADS - 1);
  const int b = bh >> 4;
  const int s0 = chunk * CHUNK;

  const bf16_t* Kb = QKV + (size_t)b * S_LEN * QKVN + DMODEL + h * HDIM;
  const bf16_t* Vb = QKV + (size_t)b * S_LEN * QKVN + 2 * DMODEL + h * HDIM;

#pragma unroll
  for (int j = 0; j < 9; ++j) {
    const int i = j * 256 + tid;
    if (i < TROWS * 8) {
      const int tr = i >> 3;
      const int slot = i & 7;
      const int c = slot ^ (tr & 7);
      int gs = s0 - 2 + tr;
      gs = (gs < 0) ? 0 : (gs >= S_LEN ? S_LEN - 1 : gs);
      async16((const char*)(Kb + (size_t)gs * QKVN) + c * 16,
              (char*)ldsK + i * 16);
      async16((const char*)(Vb + (size_t)gs * QKVN) + c * 16,
              (char*)ldsV + i * 16);
    }
  }

  const int s = s0 + tid;
  const bf16_t* Qrow = QKV + ((size_t)(b * S_LEN) + s) * QKVN + h * HDIM;
  bf16x8 q8[8];
#pragma unroll
  for (int c = 0; c < 8; ++c) q8[c] = *(const bf16x8*)(Qrow + c * 8);
  float qf[64];
#pragma unroll
  for (int c = 0; c < 8; ++c)
#pragma unroll
    for (int e = 0; e < 8; ++e) qf[c * 8 + e] = (float)q8[c][e];

  __syncthreads();

  float sc[5];
#pragma unroll
  for (int jj = 0; jj < 5; ++jj) {
    const int tr = tid + jj;
    float d = 0.f;
#pragma unroll
    for (int c = 0; c < 8; ++c) {
      const bf16x8 k8 = *(const bf16x8*)(ldsK + tr * HDIM + (c ^ (tr & 7)) * 8);
#pragma unroll
      for (int e = 0; e < 8; ++e) d += qf[c * 8 + e] * (float)k8[e];
    }
    const int j = s - 2 + jj;
    sc[jj] = (j < 0 || j >= S_LEN) ? -1e30f : d * 0.125f;
  }

  float m = sc[0];
#pragma unroll
  for (int jj = 1; jj < 5; ++jj) m = fmaxf(m, sc[jj]);
  float p[5], l = 0.f;
#pragma unroll
  for (int jj = 0; jj < 5; ++jj) {
    p[jj] = __expf(sc[jj] - m);
    l += p[jj];
  }
  const float inv = 1.0f / l;
#pragma unroll
  for (int jj = 0; jj < 5; ++jj) p[jj] *= inv;

  float o[64];
#pragma unroll
  for (int e = 0; e < 64; ++e) o[e] = 0.f;
#pragma unroll
  for (int jj = 0; jj < 5; ++jj) {
    const int tr = tid + jj;
    const float pj = p[jj];
#pragma unroll
    for (int c = 0; c < 8; ++c) {
      const bf16x8 v8 = *(const bf16x8*)(ldsV + tr * HDIM + (c ^ (tr & 7)) * 8);
#pragma unroll
      for (int e = 0; e < 8; ++e) o[c * 8 + e] += pj * (float)v8[e];
    }
  }

  bf16_t* Crow = (bf16_t*)ctx + ((size_t)(b * S_LEN) + s) * DMODEL + h * HDIM;
#pragma unroll
  for (int c = 0; c < 8; ++c) {
    bf16x8 ov;
#pragma unroll
    for (int e = 0; e < 8; ++e) ov[e] = (bf16_t)o[c * 8 + e];
    *(bf16x8*)(Crow + c * 8) = ov;
  }
}

extern "C" void kernel_launch(void* const* d_in, const int* in_sizes, int n_in,
                              void* d_out, int out_size, void* d_ws,
                              size_t ws_size, hipStream_t stream) {
  const float* x = (const float*)d_in[0];
  const float* Wq = (const float*)d_in[1];
  const float* bq = (const float*)d_in[2];
  const float* Wk = (const float*)d_in[3];
  const float* bk = (const float*)d_in[4];
  const float* Wv = (const float*)d_in[5];
  const float* bv = (const float*)d_in[6];
  const float* Wo = (const float*)d_in[7];
  const float* bo = (const float*)d_in[8];
  float* out = (float*)d_out;

  const size_t mat = (size_t)BROWS * DMODEL;
  const size_t wmat = (size_t)DMODEL * DMODEL;
  bf16_t* xb = (bf16_t*)d_ws;   // [xb | Wqkv | Wob] contiguous (cvt dst)
  bf16_t* Wqkv = xb + mat;      // fused [3072][1024]
  bf16_t* Wob = Wqkv + 3 * wmat;
  bf16_t* QKV = Wob + wmat;     // fused [4096][3072]
  bf16_t* ctx = QKV + 3 * mat;

  cvt_all_kernel<<<8192, 256, 0, stream>>>(x, Wq, Wk, Wv, Wo, xb);
  // QKV: 128x192 tiles -> grid 32x16 = 512 blocks = 2 blocks/CU
  gemm_qkv_kernel<<<dim3(32, 16), 256, 0, stream>>>(xb, Wqkv, bq, bk, bv,
                                                    QKV);
  attn_kernel<<<256, 256, 0, stream>>>(QKV, ctx);
  gemm_o_kernel<<<dim3(32, 8), 512, 0, stream>>>(ctx, Wob, bo, out);
}

// Round 16
// 68.020 us; speedup vs baseline: 1.1665x; 1.0790x over previous
//
#include <hip/hip_runtime.h>
#include <hip/hip_bf16.h>

typedef __bf16 bf16_t;
typedef __bf16 bf16x4 __attribute__((ext_vector_type(4)));
typedef __bf16 bf16x8 __attribute__((ext_vector_type(8)));
typedef float f32x4 __attribute__((ext_vector_type(4)));

#define S_LEN 2048
#define DMODEL 1024
#define NHEADS 16
#define HDIM 64
#define BROWS 4096   // B * S
#define QKVN 3072    // fused QKV output width

__device__ __forceinline__ void async16(const void* g, void* l) {
  __builtin_amdgcn_global_load_lds(
      (const __attribute__((address_space(1))) void*)g,
      (__attribute__((address_space(3))) void*)l, 16, 0, 0);
}

// ------------- fused f32 -> bf16 conversion (x, Wq, Wk, Wv, Wo) -------------
__global__ __launch_bounds__(256) void cvt_all_kernel(
    const float* __restrict__ x, const float* __restrict__ Wq,
    const float* __restrict__ Wk, const float* __restrict__ Wv,
    const float* __restrict__ Wo, bf16_t* __restrict__ dst) {
  const int i = blockIdx.x * 256 + threadIdx.x;  // float4 index
  constexpr int XN4 = (BROWS * DMODEL) / 4;      // 1048576
  constexpr int WN4 = (DMODEL * DMODEL) / 4;     // 262144
  const float* src;
  size_t off;
  if (i < XN4) {
    src = x;
    off = (size_t)i;
  } else {
    const int wi = i - XN4;
    const int w = wi >> 18;
    off = (size_t)(wi & (WN4 - 1));
    src = (w == 0) ? Wq : (w == 1) ? Wk : (w == 2) ? Wv : Wo;
  }
  const float4 v = *(const float4*)(src + off * 4);
  bf16x4 o;
  o[0] = (bf16_t)v.x;
  o[1] = (bf16_t)v.y;
  o[2] = (bf16_t)v.z;
  o[3] = (bf16_t)v.w;
  *(bf16x4*)(dst + (size_t)i * 4) = o;
}

#define BARR __builtin_amdgcn_s_barrier()
#define LGKM0 asm volatile("s_waitcnt lgkmcnt(0)" ::: "memory")
#define VMC10 asm volatile("s_waitcnt vmcnt(10)" ::: "memory")
#define VMC12 asm volatile("s_waitcnt vmcnt(12)" ::: "memory")
#define VMC0 asm volatile("s_waitcnt vmcnt(0)" ::: "memory")

// ========== 128x192 GEMM (QKV): 2 blocks/CU, independent barrier domains ====
// (r15, verified: reads -> LGKM0 -> BARR#1 -> stage(t+2) -> MFMA ->
//  VMC(<=10) -> BARR#2; 10 stage-instr/tile; swizzle slot^(row&7).)
__global__ __launch_bounds__(256, 2) void gemm_qkv_kernel(
    const bf16_t* __restrict__ A, const bf16_t* __restrict__ W,
    const float* __restrict__ bq, const float* __restrict__ bk,
    const float* __restrict__ bv, bf16_t* __restrict__ C) {
  constexpr int Kd = 1024;
  __shared__ char lds[81920];  // A: 2buf*16KB, B: 2buf*24KB = 80KB
  char* ldsA = lds;            // + buf*16384
  char* ldsB = lds + 32768;    // + buf*24576

  const int m0 = blockIdx.x * 128;
  const int n0 = blockIdx.y * 192;

  const int tid = threadIdx.x;
  const int lane = tid & 63;
  const int wid = tid >> 6;   // 0..3
  const int wr = wid >> 1;    // 0..1 (64 rows each)
  const int wc = wid & 1;     // 0..1 (96 cols each)
  const int fr = lane & 15;
  const int l16 = lane >> 4;

  f32x4 acc[4][6] = {};
  bf16x8 aS[4][2], bB[6][2];

  auto stageA = [&](int buf, int kt) {
#pragma unroll
    for (int l = 0; l < 4; ++l) {
      const int idx = l * 256 + tid;
      const int r = idx >> 3;  // 0..127
      const int slot = idx & 7;
      async16((const char*)(A + (size_t)(m0 + r) * Kd + kt * 64 +
                            ((slot ^ (r & 7)) << 3)),
              ldsA + buf * 16384 + r * 128 + slot * 16);
    }
  };
  auto stageB = [&](int buf, int kt) {
#pragma unroll
    for (int l = 0; l < 6; ++l) {
      const int idx = l * 256 + tid;
      const int r = idx >> 3;  // 0..191
      const int slot = idx & 7;
      async16((const char*)(W + (size_t)(n0 + r) * Kd + kt * 64 +
                            ((slot ^ (r & 7)) << 3)),
              ldsB + buf * 24576 + r * 128 + slot * 16);
    }
  };

  auto rdA = [&](int buf, int row, int ks) -> bf16x8 {
    return *(const bf16x8*)(ldsA + buf * 16384 + row * 128 +
                            ((((ks << 2) + l16) ^ (row & 7)) << 4));
  };
  auto rdB = [&](int buf, int row, int ks) -> bf16x8 {
    return *(const bf16x8*)(ldsB + buf * 24576 + row * 128 +
                            ((((ks << 2) + l16) ^ (row & 7)) << 4));
  };

  stageA(0, 0);
  stageB(0, 0);
  stageA(1, 1);
  stageB(1, 1);
  VMC10;  // 20 outstanding -> retire oldest 10 = all of tile0 (own)
  BARR;   // barrier-release certifies tile0 across all waves

#pragma unroll 1
  for (int t = 0; t < 16; ++t) {
    const int buf = t & 1;
#pragma unroll
    for (int m_ = 0; m_ < 4; ++m_)
#pragma unroll
      for (int ks_ = 0; ks_ < 2; ++ks_)
        aS[m_][ks_] = rdA(buf, wr * 64 + m_ * 16 + fr, ks_);
#pragma unroll
    for (int n_ = 0; n_ < 6; ++n_)
#pragma unroll
      for (int ks_ = 0; ks_ < 2; ++ks_)
        bB[n_][ks_] = rdB(buf, wc * 96 + n_ * 16 + fr, ks_);
    LGKM0;
    BARR;
    if (t + 2 < 16) {
      stageA(buf, t + 2);
      stageB(buf, t + 2);
    }
    __builtin_amdgcn_s_setprio(1);
#pragma unroll
    for (int m_ = 0; m_ < 4; ++m_)
#pragma unroll
      for (int n_ = 0; n_ < 6; ++n_)
#pragma unroll
        for (int ks_ = 0; ks_ < 2; ++ks_)
          acc[m_][n_] = __builtin_amdgcn_mfma_f32_16x16x32_bf16(
              aS[m_][ks_], bB[n_][ks_], acc[m_][n_], 0, 0, 0);
    __builtin_amdgcn_s_setprio(0);
    if (t < 15) {
      if (t + 2 < 16) {
        VMC10;
      } else {
        VMC0;
      }
      BARR;
    }
  }

  const int cr = l16 * 4;
#pragma unroll
  for (int nf = 0; nf < 6; ++nf) {
    const int col = n0 + wc * 96 + nf * 16 + fr;  // 0..3071
    const int mat = col >> 10;
    const float* bp = (mat == 0) ? bq : (mat == 1) ? bk : bv;
    const float bval = bp[col & 1023];
#pragma unroll
    for (int mf = 0; mf < 4; ++mf) {
      const int row = m0 + wr * 64 + mf * 16 + cr;
#pragma unroll
      for (int r = 0; r < 4; ++r)
        C[(size_t)(row + r) * QKVN + col] = (bf16_t)(acc[mf][nf][r] + bval);
    }
  }
}

// ====== 64x128 GEMM (O-proj): r15 template, 2 waves, 2 blocks/CU ============
// Round-16: old O was grid 256 = 1 blk/CU lockstep (r14-diagnosed shape).
// New: tile 64x128, BK=64, 128 thr (2 waves, wave-tile 64x64 = best LDS
// ratio), grid 64x8 = 512 = 2 blocks/CU, XOR swizzle, r15 race-free loop.
// Ledger: 12 stage-instr/tile (A4+B8); prologue 24 -> VMC12 retires tile0;
// steady 24 -> VMC12 retires t+1; t=14 -> VMC0.
__global__ __launch_bounds__(128) void gemm_o_kernel(
    const bf16_t* __restrict__ A, const bf16_t* __restrict__ W,
    const float* __restrict__ bias, float* __restrict__ out) {
  constexpr int Kd = 1024, Nd = 1024;
  __shared__ char lds[49152];  // A: 2buf*8KB = 16KB, B: 2buf*16KB = 32KB
  char* ldsA = lds;            // + buf*8192
  char* ldsB = lds + 16384;    // + buf*16384

  const int m0 = blockIdx.x * 64;
  const int n0 = blockIdx.y * 128;

  const int tid = threadIdx.x;  // 0..127
  const int lane = tid & 63;
  const int wid = tid >> 6;  // 0..1 (64-col halves)
  const int fr = lane & 15;
  const int l16 = lane >> 4;

  f32x4 acc[4][4] = {};
  bf16x8 aS[4][2], bB[4][2];

  // A tile: 64 rows x 128B = 512 chunks -> 4 instr/thread
  auto stageA = [&](int buf, int kt) {
#pragma unroll
    for (int l = 0; l < 4; ++l) {
      const int idx = l * 128 + tid;
      const int r = idx >> 3;  // 0..63
      const int slot = idx & 7;
      async16((const char*)(A + (size_t)(m0 + r) * Kd + kt * 64 +
                            ((slot ^ (r & 7)) << 3)),
              ldsA + buf * 8192 + r * 128 + slot * 16);
    }
  };
  // B tile: 128 rows x 128B = 1024 chunks -> 8 instr/thread
  auto stageB = [&](int buf, int kt) {
#pragma unroll
    for (int l = 0; l < 8; ++l) {
      const int idx = l * 128 + tid;
      const int r = idx >> 3;  // 0..127
      const int slot = idx & 7;
      async16((const char*)(W + (size_t)(n0 + r) * Kd + kt * 64 +
                            ((slot ^ (r & 7)) << 3)),
              ldsB + buf * 16384 + r * 128 + slot * 16);
    }
  };

  auto rdA = [&](int buf, int row, int ks) -> bf16x8 {
    return *(const bf16x8*)(ldsA + buf * 8192 + row * 128 +
                            ((((ks << 2) + l16) ^ (row & 7)) << 4));
  };
  auto rdB = [&](int buf, int row, int ks) -> bf16x8 {
    return *(const bf16x8*)(ldsB + buf * 16384 + row * 128 +
                            ((((ks << 2) + l16) ^ (row & 7)) << 4));
  };

  stageA(0, 0);
  stageB(0, 0);
  stageA(1, 1);
  stageB(1, 1);
  VMC12;  // 24 outstanding -> retire oldest 12 = all of tile0 (own)
  BARR;   // certify tile0 across both waves

#pragma unroll 1
  for (int t = 0; t < 16; ++t) {
    const int buf = t & 1;
    // reads: A 8 + B 8 = 16 x ds_read_b128 per wave
#pragma unroll
    for (int m_ = 0; m_ < 4; ++m_)
#pragma unroll
      for (int ks_ = 0; ks_ < 2; ++ks_)
        aS[m_][ks_] = rdA(buf, m_ * 16 + fr, ks_);
#pragma unroll
    for (int n_ = 0; n_ < 4; ++n_)
#pragma unroll
      for (int ks_ = 0; ks_ < 2; ++ks_)
        bB[n_][ks_] = rdB(buf, wid * 64 + n_ * 16 + fr, ks_);
    LGKM0;  // own reads retired...
    BARR;   // ...all waves' reads retired -> buf safe to overwrite
    if (t + 2 < 16) {
      stageA(buf, t + 2);
      stageB(buf, t + 2);
    }
    __builtin_amdgcn_s_setprio(1);
#pragma unroll
    for (int m_ = 0; m_ < 4; ++m_)
#pragma unroll
      for (int n_ = 0; n_ < 4; ++n_)
#pragma unroll
        for (int ks_ = 0; ks_ < 2; ++ks_)
          acc[m_][n_] = __builtin_amdgcn_mfma_f32_16x16x32_bf16(
              aS[m_][ks_], bB[n_][ks_], acc[m_][n_], 0, 0, 0);
    __builtin_amdgcn_s_setprio(0);
    if (t < 15) {
      if (t + 2 < 16) {
        VMC12;  // outstanding t+1's 12 + t+2's 12 -> retire t+1's
      } else {
        VMC0;   // t=14: only t15's 12 outstanding
      }
      BARR;
    }
  }

  // epilogue: f32 out + bias; C/D layout col=lane&15, row=(lane>>4)*4+reg
  const int cr = l16 * 4;
#pragma unroll
  for (int nf = 0; nf < 4; ++nf) {
    const int col = n0 + wid * 64 + nf * 16 + fr;  // 0..1023
    const float bval = bias[col];
#pragma unroll
    for (int mf = 0; mf < 4; ++mf) {
      const int row = m0 + mf * 16 + cr;
#pragma unroll
      for (int r = 0; r < 4; ++r)
        out[(size_t)(row + r) * Nd + col] = acc[mf][nf][r] + bval;
    }
  }
}

// ---------------- local attention (thread-per-query, fused QKV in) ---------
#define CHUNK 256
#define TROWS 260

__global__ __launch_bounds__(256) void attn_kernel(
    const bf16_t* __restrict__ QKV, bf16_t* __restrict__ ctx) {
  __shared__ bf16_t ldsK[TROWS * HDIM];
  __shared__ bf16_t ldsV[TROWS * HDIM];

  const int tid = threadIdx.x;
  const int blk = blockIdx.x;
  const int chunk = blk & 7;
  const int bh = blk >> 3;
  const int h = bh & (NHEADS - 1);
  const int b = bh >> 4;
  const int s0 = chunk * CHUNK;

  const bf16_t* Kb = QKV + (size_t)b * S_LEN * QKVN + DMODEL + h * HDIM;
  const bf16_t* Vb = QKV + (size_t)b * S_LEN * QKVN + 2 * DMODEL + h * HDIM;

#pragma unroll
  for (int j = 0; j < 9; ++j) {
    const int i = j * 256 + tid;
    if (i < TROWS * 8) {
      const int tr = i >> 3;
      const int slot = i & 7;
      const int c = slot ^ (tr & 7);
      int gs = s0 - 2 + tr;
      gs = (gs < 0) ? 0 : (gs >= S_LEN ? S_LEN - 1 : gs);
      async16((const char*)(Kb + (size_t)gs * QKVN) + c * 16,
              (char*)ldsK + i * 16);
      async16((const char*)(Vb + (size_t)gs * QKVN) + c * 16,
              (char*)ldsV + i * 16);
    }
  }

  const int s = s0 + tid;
  const bf16_t* Qrow = QKV + ((size_t)(b * S_LEN) + s) * QKVN + h * HDIM;
  bf16x8 q8[8];
#pragma unroll
  for (int c = 0; c < 8; ++c) q8[c] = *(const bf16x8*)(Qrow + c * 8);
  float qf[64];
#pragma unroll
  for (int c = 0; c < 8; ++c)
#pragma unroll
    for (int e = 0; e < 8; ++e) qf[c * 8 + e] = (float)q8[c][e];

  __syncthreads();

  float sc[5];
#pragma unroll
  for (int jj = 0; jj < 5; ++jj) {
    const int tr = tid + jj;
    float d = 0.f;
#pragma unroll
    for (int c = 0; c < 8; ++c) {
      const bf16x8 k8 = *(const bf16x8*)(ldsK + tr * HDIM + (c ^ (tr & 7)) * 8);
#pragma unroll
      for (int e = 0; e < 8; ++e) d += qf[c * 8 + e] * (float)k8[e];
    }
    const int j = s - 2 + jj;
    sc[jj] = (j < 0 || j >= S_LEN) ? -1e30f : d * 0.125f;
  }

  float m = sc[0];
#pragma unroll
  for (int jj = 1; jj < 5; ++jj) m = fmaxf(m, sc[jj]);
  float p[5], l = 0.f;
#pragma unroll
  for (int jj = 0; jj < 5; ++jj) {
    p[jj] = __expf(sc[jj] - m);
    l += p[jj];
  }
  const float inv = 1.0f / l;
#pragma unroll
  for (int jj = 0; jj < 5; ++jj) p[jj] *= inv;

  float o[64];
#pragma unroll
  for (int e = 0; e < 64; ++e) o[e] = 0.f;
#pragma unroll
  for (int jj = 0; jj < 5; ++jj) {
    const int tr = tid + jj;
    const float pj = p[jj];
#pragma unroll
    for (int c = 0; c < 8; ++c) {
      const bf16x8 v8 = *(const bf16x8*)(ldsV + tr * HDIM + (c ^ (tr & 7)) * 8);
#pragma unroll
      for (int e = 0; e < 8; ++e) o[c * 8 + e] += pj * (float)v8[e];
    }
  }

  bf16_t* Crow = (bf16_t*)ctx + ((size_t)(b * S_LEN) + s) * DMODEL + h * HDIM;
#pragma unroll
  for (int c = 0; c < 8; ++c) {
    bf16x8 ov;
#pragma unroll
    for (int e = 0; e < 8; ++e) ov[e] = (bf16_t)o[c * 8 + e];
    *(bf16x8*)(Crow + c * 8) = ov;
  }
}

extern "C" void kernel_launch(void* const* d_in, const int* in_sizes, int n_in,
                              void* d_out, int out_size, void* d_ws,
                              size_t ws_size, hipStream_t stream) {
  const float* x = (const float*)d_in[0];
  const float* Wq = (const float*)d_in[1];
  const float* bq = (const float*)d_in[2];
  const float* Wk = (const float*)d_in[3];
  const float* bk = (const float*)d_in[4];
  const float* Wv = (const float*)d_in[5];
  const float* bv = (const float*)d_in[6];
  const float* Wo = (const float*)d_in[7];
  const float* bo = (const float*)d_in[8];
  float* out = (float*)d_out;

  const size_t mat = (size_t)BROWS * DMODEL;
  const size_t wmat = (size_t)DMODEL * DMODEL;
  bf16_t* xb = (bf16_t*)d_ws;   // [xb | Wqkv | Wob] contiguous (cvt dst)
  bf16_t* Wqkv = xb + mat;      // fused [3072][1024]
  bf16_t* Wob = Wqkv + 3 * wmat;
  bf16_t* QKV = Wob + wmat;     // fused [4096][3072]
  bf16_t* ctx = QKV + 3 * mat;

  cvt_all_kernel<<<8192, 256, 0, stream>>>(x, Wq, Wk, Wv, Wo, xb);
  // QKV: 128x192 tiles -> grid 32x16 = 512 blocks = 2 blocks/CU
  gemm_qkv_kernel<<<dim3(32, 16), 256, 0, stream>>>(xb, Wqkv, bq, bk, bv,
                                                    QKV);
  attn_kernel<<<256, 256, 0, stream>>>(QKV, ctx);
  // O: 64x128 tiles -> grid 64x8 = 512 blocks = 2 blocks/CU
  gemm_o_kernel<<<dim3(64, 8), 128, 0, stream>>>(ctx, Wob, bo, out);
}